// Round 11
// baseline (1008.387 us; speedup 1.0000x reference)
//
#include <hip/hip_runtime.h>
#include <hip/hip_bf16.h>

#define IN_F 4096
#define OUT_F 11008

typedef __bf16 bf16_t;
typedef bf16_t bf16x8 __attribute__((ext_vector_type(8)));
typedef float f32x4 __attribute__((ext_vector_type(4)));
typedef unsigned int u32;

// ============================ pass 1a: x f32 -> bf16 ============================
__global__ __launch_bounds__(256) void cvt_x_kernel(const float* __restrict__ x,
                                                    bf16_t* __restrict__ xb) {
    size_t i = ((size_t)blockIdx.x * 256 + threadIdx.x) * 8;
    f32x4 v0 = __builtin_nontemporal_load((const f32x4*)(x + i));
    f32x4 v1 = __builtin_nontemporal_load((const f32x4*)(x + i + 4));
    bf16x8 h;
    h[0]=(bf16_t)v0[0]; h[1]=(bf16_t)v0[1]; h[2]=(bf16_t)v0[2]; h[3]=(bf16_t)v0[3];
    h[4]=(bf16_t)v1[0]; h[5]=(bf16_t)v1[1]; h[6]=(bf16_t)v1[2]; h[7]=(bf16_t)v1[3];
    *(bf16x8*)(xb + i) = h;
}

// ============ pass 1b: dequant qweight -> Wt[n][k] bf16 (B^T layout) ============
__global__ __launch_bounds__(256) void dequant_kernel(const int* __restrict__ qweight,
                                                      const float* __restrict__ scales,
                                                      const int* __restrict__ qzeros,
                                                      bf16_t* __restrict__ wt) {
    const int n   = blockIdx.x * 256 + threadIdx.x;
    const int kw0 = blockIdx.y * 4;
    const int g   = kw0 >> 4;
    const float s  = scales[(size_t)g * OUT_F + n];
    const int   zw = qzeros[(size_t)g * (OUT_F / 8) + (n >> 3)];
    const float nsz = -s * (float)(((zw >> ((n & 7) * 4)) & 0xF) + 1);
    bf16_t* dst = wt + (size_t)n * IN_F + kw0 * 8;
    #pragma unroll
    for (int j = 0; j < 4; ++j) {
        const int w = __builtin_nontemporal_load(&qweight[(size_t)(kw0 + j) * OUT_F + n]);
        bf16x8 h;
        #pragma unroll
        for (int b = 0; b < 8; ++b)
            h[b] = (bf16_t)fmaf((float)((w >> (4 * b)) & 0xF), s, nsz);
        *(bf16x8*)(dst + j * 8) = h;
    }
}

// ================== pass 2: 256x256 bf16 B^T GEMM, 4 waves x 128x128 ==================
// R10: geometry change. 4 waves (2Mx2N), wave tile 128x128 -> LDS read
// amplification 2x/2x (was 4x/2x): 128 b128 reads/K-tile/CU (384 cyc/phase)
// vs MFMA 592 cyc/phase -> MFMA is the long pipe. 1 wave/SIMD -> all operands
// prefetched >=1 phase ahead into DOUBLE register sets (budget 512 VGPR/wave):
// acc 8x8 (256 AGPR) + A 2x64 + B 2x16 + addr ~ 450.
// Reads 8/phase (4 A-prefetch + 4 B-next); stage 1 half-tile (4 loads)/phase;
// vmcnt ring: (8)@ph3, (4)@ph4, (8)@ph7, (8)@ph8.

#define NI (IN_F / 128)   // 32 iterations, 64 K-tiles

__global__ __launch_bounds__(256, 1) void gemm_4w(const bf16_t* __restrict__ A,
                                                  const bf16_t* __restrict__ B,
                                                  float* __restrict__ C) {
    __shared__ __align__(16) bf16_t smemA[2 * 2 * 128 * 64];   // 64 KiB
    __shared__ __align__(16) bf16_t smemB[2 * 2 * 128 * 64];   // 64 KiB

    const int tid  = threadIdx.x;
    const int lane = tid & 63;
    const int wid  = tid >> 6;      // 0..3
    const int wr   = wid >> 1;      // 0..1  (M half)
    const int wc   = wid & 1;       // 0..1  (N half)

    // bijective XCD swizzle: nwg = 1376 = 8*172
    const int bid = blockIdx.x;
    const int swz = (bid & 7) * 172 + (bid >> 3);
    const int bx = swz % 43;
    const int by = swz / 43;
    const int m0 = by * 256;
    const int n0 = bx * 256;

    // staging map: 4 slots/thread (16KB half-tile = 4 x 4KB), inverse-swizzled
    int offg[4];
    #pragma unroll
    for (int j = 0; j < 4; ++j) {
        int L = j * 4096 + tid * 16;
        int p = L ^ (((L >> 7) & 7) << 4);
        offg[j] = (p >> 7) * IN_F + ((p & 127) >> 1);
    }

    // fragment-read swizzled column byte offsets within a 128B row
    const int xm = (lane & 7) << 4;
    const int arow = lane & 15;
    int colk[2];
    #pragma unroll
    for (int ks = 0; ks < 2; ++ks)
        colk[ks] = ((ks * 64) + ((lane >> 4) * 16)) ^ xm;

    const bf16_t* gA = A + (size_t)m0 * IN_F;
    const bf16_t* gB = B + (size_t)n0 * IN_F;

#define STAGE_HALF(smem_, gbase_, buf, half, koff)                                         \
    _Pragma("unroll") for (int j = 0; j < 4; ++j) {                                        \
        __builtin_amdgcn_global_load_lds(                                                  \
            (const __attribute__((address_space(1))) u32*)                                 \
                ((gbase_) + (size_t)(half) * (128 * IN_F) + (koff) + offg[j]),             \
            (__attribute__((address_space(3))) u32*)((char*)(smem_) + (buf) * 32768 +      \
                (half) * 16384 + j * 4096 + wid * 1024),                                   \
            16, 0, 0);                                                                     \
    }

// 4 ds_read_b128: A fragments m-tiles mg, mg+1 (x2 k-slices) into dst[(mg+mm)*2+ks]
#define RD_A2(dst, buf, mg)                                                                \
    _Pragma("unroll") for (int mm = 0; mm < 2; ++mm)                                       \
    _Pragma("unroll") for (int ks = 0; ks < 2; ++ks)                                       \
        dst[((mg) + mm) * 2 + ks] = *(const bf16x8*)((const char*)smemA + (buf) * 32768 +  \
            wr * 16384 + (((mg) + mm) * 16 + arow) * 128 + colk[ks]);

// 4 ds_read_b128: B pair np (2 n-tiles x 2 ks) into dst[nn*2+ks]
#define RD_B(dst, buf, np)                                                                 \
    _Pragma("unroll") for (int nn = 0; nn < 2; ++nn)                                       \
    _Pragma("unroll") for (int ks = 0; ks < 2; ++ks)                                       \
        dst[nn * 2 + ks] = *(const bf16x8*)((const char*)smemB + (buf) * 32768 +           \
            wc * 16384 + ((np) * 32 + nn * 16 + arow) * 128 + colk[ks]);

// 32 MFMA: 8 m x 2 n x 2 ks for n-pair np
#define MFMA_P(aArr, bArr, np)                                                             \
    _Pragma("unroll") for (int mm = 0; mm < 8; ++mm)                                       \
    _Pragma("unroll") for (int nn = 0; nn < 2; ++nn)                                       \
    _Pragma("unroll") for (int ks = 0; ks < 2; ++ks)                                       \
        acc[mm][(np) * 2 + nn] = __builtin_amdgcn_mfma_f32_16x16x32_bf16(                  \
            aArr[mm * 2 + ks], bArr[nn * 2 + ks], acc[mm][(np) * 2 + nn], 0, 0, 0);

#define BAR() __builtin_amdgcn_s_barrier()
#define VMCNT8() asm volatile("s_waitcnt vmcnt(8)" ::: "memory")
#define VMCNT4() asm volatile("s_waitcnt vmcnt(4)" ::: "memory")
#define VMCNT0() asm volatile("s_waitcnt vmcnt(0)" ::: "memory")

    f32x4 acc[8][8];
    #pragma unroll
    for (int m = 0; m < 8; ++m)
        #pragma unroll
        for (int n = 0; n < 8; ++n)
            acc[m][n] = (f32x4)0.0f;

    bf16x8 aS0[16], aS1[16], bS0[4], bS1[4];

    // prologue: stage T0 (buf0: A,B) then T1 (buf1: A,B); confirm thru T1-A.
    STAGE_HALF(smemA, gA, 0, 0, 0); STAGE_HALF(smemA, gA, 0, 1, 0);
    STAGE_HALF(smemB, gB, 0, 0, 0); STAGE_HALF(smemB, gB, 0, 1, 0);
    STAGE_HALF(smemA, gA, 1, 0, 64); STAGE_HALF(smemA, gA, 1, 1, 64);
    STAGE_HALF(smemB, gB, 1, 0, 64); STAGE_HALF(smemB, gB, 1, 1, 64);
    VMCNT8();          // T0 + T1-A landed; T1-B (8) in flight = steady entry state
    BAR();
    // pre-reads (what steady ph5-8 would have done): full A(buf0) + B01(buf0)
    RD_A2(aS0, 0, 0); RD_A2(aS0, 0, 2); RD_A2(aS0, 0, 4); RD_A2(aS0, 0, 6);
    RD_B(bS1, 0, 0);

    for (int i = 0; i < NI; ++i) {
        const int  kn = i * 128 + 128;  // K-offset of T2 (buf0); T3 = kn+64 (buf1)
        const bool nl = (i + 1 < NI);

        // ph1 (N01, buf0): read aS1 m0-1(buf1), B23(buf0); stage A-buf0-h0(T2)
        RD_A2(aS1, 1, 0);
        RD_B(bS0, 0, 1);
        if (nl) STAGE_HALF(smemA, gA, 0, 0, kn);
        MFMA_P(aS0, bS1, 0);
        BAR();
        // ph2 (N23, buf0): read aS1 m2-3, B45(buf0); stage A-buf0-h1(T2)
        RD_A2(aS1, 1, 2);
        RD_B(bS1, 0, 2);
        if (nl) STAGE_HALF(smemA, gA, 0, 1, kn);
        MFMA_P(aS0, bS0, 1);
        BAR();
        // ph3 (N45, buf0): read aS1 m4-5, B67(buf0); confirm B(buf1) [prev ph8]
        RD_A2(aS1, 1, 4);
        RD_B(bS0, 0, 3);
        MFMA_P(aS0, bS1, 2);
        if (nl) VMCNT8(); else VMCNT0();
        BAR();
        // ph4 (N67, buf0): read aS1 m6-7, B01(buf1); stage B-buf0-h0(T2); confirm A-buf0(T2)
        RD_A2(aS1, 1, 6);
        RD_B(bS1, 1, 0);
        if (nl) STAGE_HALF(smemB, gB, 0, 0, kn);
        MFMA_P(aS0, bS0, 3);
        if (nl) VMCNT4();
        BAR();
        // ph5 (N01, buf1): read aS0 m0-1(buf0,T2), B23(buf1); stage B-buf0-h1(T2)
        if (nl) RD_A2(aS0, 0, 0);
        RD_B(bS0, 1, 1);
        if (nl) STAGE_HALF(smemB, gB, 0, 1, kn);
        MFMA_P(aS1, bS1, 0);
        BAR();
        // ph6 (N23, buf1): read aS0 m2-3, B45(buf1); stage A-buf1-h0(T3)
        if (nl) RD_A2(aS0, 0, 2);
        RD_B(bS1, 1, 2);
        if (nl) STAGE_HALF(smemA, gA, 1, 0, kn + 64);
        MFMA_P(aS1, bS0, 1);
        BAR();
        // ph7 (N45, buf1): read aS0 m4-5, B67(buf1); stage A-buf1-h1(T3); confirm B-buf0(T2)
        if (nl) RD_A2(aS0, 0, 4);
        RD_B(bS0, 1, 3);
        if (nl) STAGE_HALF(smemA, gA, 1, 1, kn + 64);
        MFMA_P(aS1, bS1, 2);
        if (nl) VMCNT8();
        BAR();
        // ph8 (N67, buf1): read aS0 m6-7, B01(buf0,T2); stage B-buf1 h0+h1(T3); confirm A-buf1(T3)
        if (nl) {
            RD_A2(aS0, 0, 6);
            RD_B(bS1, 0, 0);
            STAGE_HALF(smemB, gB, 1, 0, kn + 64);
            STAGE_HALF(smemB, gB, 1, 1, kn + 64);
        }
        MFMA_P(aS1, bS0, 3);
        if (nl) VMCNT8();
        BAR();
    }

    // epilogue: C/D layout col = lane&15, row = (lane>>4)*4 + r
    const int cn  = lane & 15;
    const int cr4 = (lane >> 4) * 4;
    #pragma unroll
    for (int m = 0; m < 8; ++m) {
        #pragma unroll
        for (int r = 0; r < 4; ++r) {
            const int grow = m0 + wr * 128 + m * 16 + cr4 + r;
            float* orow = C + (size_t)grow * OUT_F + n0 + wc * 128 + cn;
            #pragma unroll
            for (int n = 0; n < 8; ++n)
                orow[n * 16] = acc[m][n][r];
        }
    }
}

// ===================== fallback: fused kernel (R0 structure) =====================
#define BMf 128
#define BNf 128
#define BKf 32
#define LDPF 40

__global__ __launch_bounds__(256, 2) void gptq_gemm_fused(
    const float* __restrict__ x, const int* __restrict__ qweight,
    const float* __restrict__ scales, const int* __restrict__ qzeros,
    float* __restrict__ out)
{
    __shared__ bf16_t As[BMf * LDPF];
    __shared__ bf16_t Bs[BNf * LDPF];
    const int tid = threadIdx.x, lane = tid & 63, wid = tid >> 6;
    const int wr = wid >> 1, wc = wid & 1;
    const int m0 = blockIdx.y * BMf, n0 = blockIdx.x * BNf;
    const int a_row = tid >> 2, a_slot = tid & 3;
    const int b_k8l = tid >> 7, b_n = tid & 127;

    f32x4 acc[4][4];
    #pragma unroll
    for (int i = 0; i < 4; ++i)
        #pragma unroll
        for (int j = 0; j < 4; ++j) acc[i][j] = (f32x4)0.0f;

    for (int kt = 0; kt < IN_F / BKf; ++kt) {
        const int k0 = kt * BKf;
        const int g  = k0 >> 7;
        __syncthreads();
        #pragma unroll
        for (int p = 0; p < 2; ++p) {
            const int row = a_row + p * 64;
            const float* src = x + (size_t)(m0 + row) * IN_F + k0 + a_slot * 8;
            f32x4 v0 = *(const f32x4*)src;
            f32x4 v1 = *(const f32x4*)(src + 4);
            bf16x8 h;
            h[0]=(bf16_t)v0[0]; h[1]=(bf16_t)v0[1]; h[2]=(bf16_t)v0[2]; h[3]=(bf16_t)v0[3];
            h[4]=(bf16_t)v1[0]; h[5]=(bf16_t)v1[1]; h[6]=(bf16_t)v1[2]; h[7]=(bf16_t)v1[3];
            *(bf16x8*)(&As[row * LDPF + a_slot * 8]) = h;
        }
        {
            const int gn = n0 + b_n;
            const float s  = scales[(size_t)g * OUT_F + gn];
            const int   zw = qzeros[(size_t)g * (OUT_F / 8) + (gn >> 3)];
            const float sz = s * (float)(((zw >> ((gn & 7) * 4)) & 0xF) + 1);
            #pragma unroll
            for (int p = 0; p < 2; ++p) {
                const int k8l = b_k8l + p * 2;
                const int w = qweight[(size_t)(k0 / 8 + k8l) * OUT_F + gn];
                bf16x8 h;
                #pragma unroll
                for (int j = 0; j < 8; ++j)
                    h[j] = (bf16_t)fmaf((float)((w >> (4 * j)) & 0xF), s, -sz);
                *(bf16x8*)(&Bs[b_n * LDPF + k8l * 8]) = h;
            }
        }
        __syncthreads();
        bf16x8 af[4], bfr[4];
        #pragma unroll
        for (int m = 0; m < 4; ++m)
            af[m] = *(const bf16x8*)(&As[(wr * 64 + m * 16 + (lane & 15)) * LDPF + (lane >> 4) * 8]);
        #pragma unroll
        for (int n = 0; n < 4; ++n)
            bfr[n] = *(const bf16x8*)(&Bs[(wc * 64 + n * 16 + (lane & 15)) * LDPF + (lane >> 4) * 8]);
        #pragma unroll
        for (int m = 0; m < 4; ++m)
            #pragma unroll
            for (int n = 0; n < 4; ++n)
                acc[m][n] = __builtin_amdgcn_mfma_f32_16x16x32_bf16(af[m], bfr[n], acc[m][n], 0, 0, 0);
    }
    const int cn = lane & 15, cr4 = (lane >> 4) * 4;
    #pragma unroll
    for (int m = 0; m < 4; ++m)
        #pragma unroll
        for (int r = 0; r < 4; ++r) {
            const int grow = m0 + wr * 64 + m * 16 + cr4 + r;
            float* orow = out + (size_t)grow * OUT_F + n0 + wc * 64 + cn;
            #pragma unroll
            for (int n = 0; n < 4; ++n) orow[n * 16] = acc[m][n][r];
        }
}

extern "C" void kernel_launch(void* const* d_in, const int* in_sizes, int n_in,
                              void* d_out, int out_size, void* d_ws, size_t ws_size,
                              hipStream_t stream) {
    const float* x       = (const float*)d_in[0];
    const int*   qweight = (const int*)d_in[1];
    const float* scales  = (const float*)d_in[2];
    const int*   qzeros  = (const int*)d_in[3];
    float* out = (float*)d_out;

    const int M = in_sizes[0] / IN_F;                       // 8192
    const size_t xb_bytes = (size_t)M * IN_F * 2;
    const size_t wt_bytes = (size_t)IN_F * OUT_F * 2;

    if (ws_size >= xb_bytes + wt_bytes && (M % 256) == 0) {
        bf16_t* xb = (bf16_t*)d_ws;
        bf16_t* wt = (bf16_t*)((char*)d_ws + xb_bytes);
        cvt_x_kernel<<<dim3((M * IN_F) / (256 * 8)), dim3(256), 0, stream>>>(x, xb);
        dequant_kernel<<<dim3(OUT_F / 256, IN_F / 32), dim3(256), 0, stream>>>(
            qweight, scales, qzeros, wt);
        const int nwg = (OUT_F / 256) * (M / 256);          // 43*32 = 1376
        gemm_4w<<<dim3(nwg), dim3(256), 0, stream>>>(xb, wt, out);
    } else {
        gptq_gemm_fused<<<dim3(OUT_F / BNf, M / BMf), dim3(256), 0, stream>>>(
            x, qweight, scales, qzeros, out);
    }
}